// Round 16
// baseline (1098.507 us; speedup 1.0000x reference)
//
#include <hip/hip_runtime.h>

typedef unsigned short u16;
typedef unsigned int u32;
typedef __attribute__((ext_vector_type(8))) short bf16x8;
typedef __attribute__((ext_vector_type(4))) float f32x4;
typedef __attribute__((ext_vector_type(16))) float f32x16;

#define NH 32
#define NKV 8
#define HD 128
#define SEQ 2048
#define DMODEL 4096
#define QKVN 6144
#define RMS_EPS 1e-6f
#define SM_SCALE 0.08838834764831845f
#define NEG_INF -1e30f

#define AS1 __attribute__((address_space(1)))
#define AS3 __attribute__((address_space(3)))

__device__ __forceinline__ u16 f2bf(float f) {
  unsigned int u = __float_as_uint(f);
  u += 0x7FFFu + ((u >> 16) & 1u);
  return (u16)(u >> 16);
}
__device__ __forceinline__ float bf2f(u16 b) {
  return __uint_as_float(((unsigned int)b) << 16);
}
__device__ __forceinline__ u32 packbf(float lo, float hi) {
  u32 a = __float_as_uint(lo) + 0x8000u;
  u32 b = __float_as_uint(hi) + 0x8000u;
  return __builtin_amdgcn_perm(b, a, 0x07060302u);
}

__device__ __forceinline__ f32x4 mfma16(bf16x8 a, bf16x8 b, f32x4 c) {
  return __builtin_amdgcn_mfma_f32_16x16x32_bf16(a, b, c, 0, 0, 0);
}
__device__ __forceinline__ f32x16 mfma32(bf16x8 a, bf16x8 b, f32x16 c) {
  return __builtin_amdgcn_mfma_f32_32x32x16_bf16(a, b, c, 0, 0, 0);
}

__device__ __forceinline__ void stage16(const u16* g, u16* l) {
  __builtin_amdgcn_global_load_lds((const AS1 u32*)g, (AS3 u32*)l, 16, 0, 0);
}

// ---------------- convert x: f32 -> bf16 ----------------
__global__ __launch_bounds__(256) void cvt_f32_bf16(const float* __restrict__ in,
                                                    u16* __restrict__ out, int n4) {
  int stride = gridDim.x * blockDim.x;
  for (int i = blockIdx.x * blockDim.x + threadIdx.x; i < n4; i += stride) {
    float4 v = ((const float4*)in)[i];
    ushort4 o;
    o.x = f2bf(v.x); o.y = f2bf(v.y); o.z = f2bf(v.z); o.w = f2bf(v.w);
    ((ushort4*)out)[i] = o;
  }
}

// ---------------- transpose-convert, 64x64 tile (r14 proven) ----------------
__device__ __forceinline__ void tconv_tile(const float* __restrict__ W, u16* __restrict__ Wt,
                                           int N, int rowoff, int n0, int k0, int tid) {
  __shared__ float t[64][66];
  int ln = tid & 63;
  int lk = tid >> 6;
#pragma unroll
  for (int i = 0; i < 16; ++i) {
    int kk = lk + i * 4;
    t[ln][kk] = W[(size_t)(k0 + kk) * N + n0 + ln];
  }
  __syncthreads();
  int kc = tid & 31;
  int nr = tid >> 5;
#pragma unroll
  for (int j = 0; j < 8; ++j) {
    int n = nr + j * 8;
    float2 f = *(const float2*)&t[n][kc * 2];
    ushort2 o;
    o.x = f2bf(f.x);
    o.y = f2bf(f.y);
    *(ushort2*)&Wt[(size_t)(rowoff + n0 + n) * DMODEL + k0 + kc * 2] = o;
  }
}

// single kernel for Wq/Wk/Wv (one launch)
__global__ __launch_bounds__(256) void tconv3(const float* __restrict__ Wq,
                                              const float* __restrict__ Wk,
                                              const float* __restrict__ Wv,
                                              u16* __restrict__ Wt) {
  int bx = blockIdx.x, k0 = blockIdx.y * 64, tid = threadIdx.x;
  if (bx < 64)       tconv_tile(Wq, Wt, DMODEL, 0, bx * 64, k0, tid);
  else if (bx < 80)  tconv_tile(Wk, Wt, NKV * HD, DMODEL, (bx - 64) * 64, k0, tid);
  else               tconv_tile(Wv, Wt, NKV * HD, DMODEL + NKV * HD, (bx - 80) * 64, k0, tid);
}

__global__ __launch_bounds__(256) void tconv(const float* __restrict__ W, u16* __restrict__ Wt,
                                             int N, int rowoff) {
  tconv_tile(W, Wt, N, rowoff, blockIdx.x * 64, blockIdx.y * 64, threadIdx.x);
}

__device__ __forceinline__ void storeC(u16* p, float v) { *p = f2bf(v); }
__device__ __forceinline__ void storeC(float* p, float v) { *p = v; }

// ---------------- GEMM db192: 128x192 tile, BK=64, explicit double-buffer (r15 proven) ----
template <typename OutT>
__global__ __launch_bounds__(256, 2) void gemm_db192(const u16* __restrict__ A,
                                                     const u16* __restrict__ Bt,
                                                     OutT* __restrict__ C, int M, int N, int K) {
  __shared__ __align__(16) u16 As[2][128 * 64];
  __shared__ __align__(16) u16 Bs[2][192 * 64];
  int nwg = gridDim.x, q8 = nwg >> 3, bid = blockIdx.x;
  int nid = (bid & 7) * q8 + (bid >> 3);
  int mt = M >> 7;
  int m0 = (nid % mt) * 128, n0 = (nid / mt) * 192;
  int tid = threadIdx.x, wave = tid >> 6, lane = tid & 63;
  int wm = (wave >> 1) * 64, wn = (wave & 1) * 96;
  f32x4 acc[4][6] = {};
  int fr = lane & 15, fq = lane >> 4;

  int srow_ = tid >> 3;
  int scol = ((tid & 7) ^ (srow_ & 7)) * 8;
  const u16* aSrc = A + (size_t)(m0 + srow_) * K + scol;
  const u16* bSrc = Bt + (size_t)(n0 + srow_) * K + scol;
  size_t rstride = (size_t)32 * K;
  int dofs = wave * 512;
  int akey = (fr & 7);

  auto stage = [&](int buf, int kb) {
#pragma unroll
    for (int i = 0; i < 4; ++i)
      stage16(aSrc + i * rstride + kb, &As[buf][0] + i * 2048 + dofs);
#pragma unroll
    for (int i = 0; i < 6; ++i)
      stage16(bSrc + i * rstride + kb, &Bs[buf][0] + i * 2048 + dofs);
  };

  int NT = K >> 6;
  stage(0, 0);
  __syncthreads();
  for (int j = 0; j < NT; ++j) {
    int cur = j & 1;
    if (j + 1 < NT) stage(cur ^ 1, (j + 1) << 6);
    const char* Ab = (const char*)&As[cur][0];
    const char* Bb = (const char*)&Bs[cur][0];
#pragma unroll
    for (int ks = 0; ks < 2; ++ks) {
      bf16x8 af[4], bfv[6];
      int slot = (ks * 4 + fq) ^ akey;
#pragma unroll
      for (int i = 0; i < 4; ++i)
        af[i] = *(const bf16x8*)(Ab + (wm + i * 16 + fr) * 128 + slot * 16);
#pragma unroll
      for (int j2 = 0; j2 < 6; ++j2)
        bfv[j2] = *(const bf16x8*)(Bb + (wn + j2 * 16 + fr) * 128 + slot * 16);
      __builtin_amdgcn_s_setprio(1);
#pragma unroll
      for (int i = 0; i < 4; ++i)
#pragma unroll
        for (int j2 = 0; j2 < 6; ++j2)
          acc[i][j2] = mfma16(af[i], bfv[j2], acc[i][j2]);
      __builtin_amdgcn_s_setprio(0);
    }
    __syncthreads();
  }
#pragma unroll
  for (int i = 0; i < 4; ++i)
#pragma unroll
    for (int j = 0; j < 6; ++j)
#pragma unroll
      for (int r = 0; r < 4; ++r) {
        int row = m0 + wm + i * 16 + fq * 4 + r;
        int col = n0 + wn + j * 16 + fr;
        storeC(&C[(size_t)row * N + col], acc[i][j][r]);
      }
}

// ---------------- GEMM db (r12 proven): 128x128, BK=64, double-buffer ----------------
template <typename OutT>
__global__ __launch_bounds__(256) void gemm_db(const u16* __restrict__ A, const u16* __restrict__ Bt,
                                               OutT* __restrict__ C, int M, int N, int K) {
  __shared__ __align__(16) u16 As[2][128 * 64];
  __shared__ __align__(16) u16 Bs[2][128 * 64];
  int nwg = gridDim.x, q8 = nwg >> 3, bid = blockIdx.x;
  int nid = (bid & 7) * q8 + (bid >> 3);
  int mt = M >> 7;
  int m0 = (nid % mt) * 128, n0 = (nid / mt) * 128;
  int tid = threadIdx.x, wave = tid >> 6, lane = tid & 63;
  int wm = (wave >> 1) * 64, wn = (wave & 1) * 64;
  f32x4 acc[4][4] = {};
  int fr = lane & 15, fq = lane >> 4;

  int srow_ = tid >> 3;
  int scol = ((tid & 7) ^ (srow_ & 7)) * 8;
  const u16* aSrc = A + (size_t)(m0 + srow_) * K + scol;
  const u16* bSrc = Bt + (size_t)(n0 + srow_) * K + scol;
  size_t rstride = (size_t)32 * K;
  int dofs = wave * 512;
  int akey = (fr & 7);

  auto stage = [&](int buf, int kb) {
#pragma unroll
    for (int i = 0; i < 4; ++i) {
      stage16(aSrc + i * rstride + kb, &As[buf][0] + i * 2048 + dofs);
      stage16(bSrc + i * rstride + kb, &Bs[buf][0] + i * 2048 + dofs);
    }
  };

  int NT = K >> 6;
  stage(0, 0);
  __syncthreads();
  for (int j = 0; j < NT; ++j) {
    int cur = j & 1;
    if (j + 1 < NT) stage(cur ^ 1, (j + 1) << 6);
    const char* Ab = (const char*)&As[cur][0];
    const char* Bb = (const char*)&Bs[cur][0];
#pragma unroll
    for (int ks = 0; ks < 2; ++ks) {
      bf16x8 af[4], bfv[4];
      int slot = (ks * 4 + fq) ^ akey;
#pragma unroll
      for (int i = 0; i < 4; ++i)
        af[i] = *(const bf16x8*)(Ab + (wm + i * 16 + fr) * 128 + slot * 16);
#pragma unroll
      for (int j2 = 0; j2 < 4; ++j2)
        bfv[j2] = *(const bf16x8*)(Bb + (wn + j2 * 16 + fr) * 128 + slot * 16);
      __builtin_amdgcn_s_setprio(1);
#pragma unroll
      for (int i = 0; i < 4; ++i)
#pragma unroll
        for (int j2 = 0; j2 < 4; ++j2)
          acc[i][j2] = mfma16(af[i], bfv[j2], acc[i][j2]);
      __builtin_amdgcn_s_setprio(0);
    }
    __syncthreads();
  }
#pragma unroll
  for (int i = 0; i < 4; ++i)
#pragma unroll
    for (int j = 0; j < 4; ++j)
#pragma unroll
      for (int r = 0; r < 4; ++r) {
        int row = m0 + wm + i * 16 + fq * 4 + r;
        int col = n0 + wn + j * 16 + fr;
        storeC(&C[(size_t)row * N + col], acc[i][j][r]);
      }
}

// ---------------- K-only RMSNorm + RoPE (Q fused into attn) ----------------
__global__ __launch_bounds__(256) void normrope_k(u16* __restrict__ QKV,
                                                  const float* __restrict__ kw) {
  int wq = threadIdx.x >> 6, lane = threadIdx.x & 63;
  int gid = blockIdx.x * 4 + wq;  // 0 .. 4096*8-1
  int token = gid >> 3, head = gid & 7;
  int pos = token & (SEQ - 1);
  u16* row = QKV + (size_t)token * QKVN + DMODEL + head * HD;
  ushort2 xv = *(const ushort2*)(row + 2 * lane);
  float x1 = bf2f(xv.x), x2 = bf2f(xv.y);
  float ssq = x1 * x1 + x2 * x2;
#pragma unroll
  for (int o = 32; o; o >>= 1) ssq += __shfl_xor(ssq, o, 64);
  float rms = rsqrtf(ssq * (1.0f / HD) + RMS_EPS);
  float y1 = x1 * rms * kw[2 * lane];
  float y2 = x2 * rms * kw[2 * lane + 1];
  float freq = exp2f((float)lane * -0.20762050593046014f);
  float ang = (float)pos * freq;
  float s, c;
  __sincosf(ang, &s, &c);
  ushort2 ov;
  ov.x = f2bf(y1 * c - y2 * s);
  ov.y = f2bf(y1 * s + y2 * c);
  *(ushort2*)(row + 2 * lane) = ov;
}

// ---------------- 8-wave 32x32 swapped-QK^T flash attention + fused Q norm/rope ----------------
// Q is read RAW from gemm1 output; RMSNorm+RoPE+SM_SCALE applied in-register per pass:
// lane (qn,hi) holds half of row q0w+qn (cols d*16+hi*8..+7); row ssq completes via
// shfl_xor(32); RoPE pair index p = d*8+hi*4+jj. K normed by normrope_k beforehand.
__global__ __launch_bounds__(512, 4) void attn(const u16* __restrict__ QKV,
                                               const float* __restrict__ qw,
                                               u16* __restrict__ O) {
  int bid0 = blockIdx.x;
  int bid = (bid0 & 7) * 32 + (bid0 >> 3);
  int pairi = bid & 3, h = (bid >> 2) & 31, b = bid >> 7;
  int tid = threadIdx.x, wave = tid >> 6, lane = tid & 63;
  int qn = lane & 31, hi = lane >> 5;
  int hi4 = hi * 4, hi16 = hi * 16;
  int kvh = h >> 2;

  __shared__ __align__(16) u16 Ks[2][64 * 128];
  __shared__ __align__(16) u16 Vs[2][128 * 64];

  size_t tokb = (size_t)b * SEQ;
  const u16* Kg = QKV + tokb * QKVN + DMODEL + kvh * HD;
  const u16* Vg = Kg + NKV * HD;
  int srow = tid >> 4, sl = tid & 15;

  int kk0 = (qn & 7) << 4;
  int d0 = qn, d1 = 32 + qn, d2 = 64 + qn, d3 = 96 + qn;
  int vk0 = ((d0 ^ (d0 >> 3)) & 7) << 4;
  int vk1 = ((d1 ^ (d1 >> 3)) & 7) << 4;
  int vk2 = ((d2 ^ (d2 >> 3)) & 7) << 4;
  int vk3 = ((d3 ^ (d3 >> 3)) & 7) << 4;

  int4 vreg[2];
  auto loadV = [&](int kv0) {
#pragma unroll
    for (int i = 0; i < 2; ++i)
      vreg[i] = *(const int4*)(Vg + (size_t)(kv0 + i * 32 + srow) * QKVN + sl * 8);
  };
  auto stageK = [&](int buf, int kv0) {
#pragma unroll
    for (int i = 0; i < 2; ++i) {
      int row = i * 32 + srow;
      __builtin_amdgcn_global_load_lds(
          (const AS1 u32*)(Kg + (size_t)(kv0 + row) * QKVN + ((sl ^ (row & 7)) * 8)),
          (AS3 u32*)(&Ks[buf][0] + (i * 32 + wave * 4) * 128), 16, 0, 0);
    }
  };
  auto packV = [&](int buf) {
#pragma unroll
    for (int i = 0; i < 2; ++i) {
      int row = i * 32 + srow;
      int4 dvi = vreg[i];
      int4 dpi;
      dpi.x = __shfl_xor(dvi.x, 16, 64);
      dpi.y = __shfl_xor(dvi.y, 16, 64);
      dpi.z = __shfl_xor(dvi.z, 16, 64);
      dpi.w = __shfl_xor(dvi.w, 16, 64);
      if (((tid >> 4) & 1) == 0) {
        const u16* own = (const u16*)&dvi;
        const u16* par = (const u16*)&dpi;
#pragma unroll
        for (int j = 0; j < 8; ++j) {
          u32 wv = (u32)own[j] | ((u32)par[j] << 16);
          int d = sl * 8 + j;
          int vk = ((d ^ (d >> 3)) & 7) << 4;
          *(u32*)((char*)&Vs[buf][0] + d * 128 + ((2 * row) ^ vk)) = wv;
        }
      }
    }
  };

  for (int pass = 0; pass < 2; ++pass) {
    int chunk = pass ? (7 - pairi) : pairi;
    int chb = chunk * 256;
    int nt = (chunk + 1) * 4;
    int q0w = chb + wave * 32;
    int qabs = q0w + qn;
    int lim = chunk * 4 + (wave >> 1);
    int diag = q0w & ~63;

    // ---- fused Q: raw load -> RMSNorm -> RoPE -> *SM_SCALE, all in-register ----
    bf16x8 qf[8];
    {
      const u16* qp = QKV + (tokb + q0w + qn) * QKVN + h * HD;
      float ssq = 0.f;
#pragma unroll
      for (int d = 0; d < 8; ++d) {
        qf[d] = *(const bf16x8*)(qp + d * 16 + hi * 8);
#pragma unroll
        for (int j = 0; j < 8; ++j) {
          float f = bf2f((u16)qf[d][j]);
          ssq += f * f;
        }
      }
      ssq += __shfl_xor(ssq, 32, 64);
      float rms = rsqrtf(ssq * (1.0f / HD) + RMS_EPS) * SM_SCALE;
      int pos = q0w + qn;  // tokb offset removed: position within sequence
#pragma unroll
      for (int d = 0; d < 8; ++d) {
        const float* wp = qw + d * 16 + hi * 8;
        union { u32 w[4]; bf16x8 v; } uo;
#pragma unroll
        for (int jj = 0; jj < 4; ++jj) {
          float y1 = bf2f((u16)qf[d][2 * jj]) * rms * wp[2 * jj];
          float y2 = bf2f((u16)qf[d][2 * jj + 1]) * rms * wp[2 * jj + 1];
          float fr8 = exp2f((float)(d * 8 + hi * 4 + jj) * -0.20762050593046014f);
          float ang = (float)pos * fr8;
          float s, c;
          __sincosf(ang, &s, &c);
          uo.w[jj] = packbf(y1 * c - y2 * s, y1 * s + y2 * c);
        }
        qf[d] = uo.v;
      }
    }

    f32x16 o0 = {}, o1 = {}, o2 = {}, o3 = {};
    float mrow = NEG_INF, lsum = 0.f;

    auto tile = [&](int kv0, const u16* Kl, const u16* Vl) {
      f32x16 p0v = {}, p1v = {};
      {
        const char* kb0 = (const char*)Kl + qn * 256;
        const char* kb1 = (const char*)Kl + (32 + qn) * 256;
        __builtin_amdgcn_s_setprio(1);
#pragma unroll
        for (int d = 0; d < 8; ++d) {
          bf16x8 k0 = *(const bf16x8*)(kb0 + ((d * 32 + hi16) ^ kk0));
          bf16x8 k1 = *(const bf16x8*)(kb1 + ((d * 32 + hi16) ^ kk0));
          p0v = mfma32(k0, qf[d], p0v);
          p1v = mfma32(k1, qf[d], p1v);
        }
        __builtin_amdgcn_s_setprio(0);
      }
      if (kv0 == diag) {
#pragma unroll
        for (int r = 0; r < 16; ++r) {
          int kva = kv0 + (r & 3) + 8 * (r >> 2) + hi4;
          if (kva > qabs) p0v[r] = NEG_INF;
          if (kva + 32 > qabs) p1v[r] = NEG_INF;
        }
      }
      float tmax = NEG_INF;
#pragma unroll
      for (int r = 0; r < 16; ++r) tmax = fmaxf(tmax, fmaxf(p0v[r], p1v[r]));
      tmax = fmaxf(tmax, __shfl_xor(tmax, 32, 64));
      if (!__all(tmax <= mrow + 8.0f)) {
        float nm = fmaxf(mrow, tmax);
        float corr = __expf(mrow - nm);
        mrow = nm;
        lsum *= corr;
#pragma unroll
        for (int r = 0; r < 16; ++r) {
          int srcl = (r & 3) + 8 * (r >> 2) + hi4;
          float cr = __shfl(corr, srcl, 64);
          o0[r] *= cr; o1[r] *= cr; o2[r] *= cr; o3[r] *= cr;
        }
      }
      float rs = 0.f;
#pragma unroll
      for (int r = 0; r < 16; ++r) {
        p0v[r] = __expf(p0v[r] - mrow);
        p1v[r] = __expf(p1v[r] - mrow);
        rs += p0v[r] + p1v[r];
      }
      rs += __shfl_xor(rs, 32, 64);
      lsum += rs;

      auto pv = [&](const f32x16& pk, int kvs) {
#pragma unroll
        for (int e = 0; e < 2; ++e) {
          u32 A = packbf(pk[e * 8 + 0], pk[e * 8 + 1]);
          u32 Bw = packbf(pk[e * 8 + 2], pk[e * 8 + 3]);
          u32 C = packbf(pk[e * 8 + 4], pk[e * 8 + 5]);
          u32 Dw = packbf(pk[e * 8 + 6], pk[e * 8 + 7]);
          u32 sA = __shfl_xor(A, 32, 64), sC = __shfl_xor(C, 32, 64);
          u32 sB = __shfl_xor(Bw, 32, 64), sD = __shfl_xor(Dw, 32, 64);
          union { u32 w[4]; bf16x8 v; } fr;
          fr.w[0] = hi ? sC : A;
          fr.w[1] = hi ? sD : Bw;
          fr.w[2] = hi ? C : sA;
          fr.w[3] = hi ? Dw : sB;
          int off = (kvs * 2 + e) * 32 + hi16;
          __builtin_amdgcn_s_setprio(1);
          o0 = mfma32(fr.v, *(const bf16x8*)((const char*)Vl + d0 * 128 + (off ^ vk0)), o0);
          o1 = mfma32(fr.v, *(const bf16x8*)((const char*)Vl + d1 * 128 + (off ^ vk1)), o1);
          o2 = mfma32(fr.v, *(const bf16x8*)((const char*)Vl + d2 * 128 + (off ^ vk2)), o2);
          o3 = mfma32(fr.v, *(const bf16x8*)((const char*)Vl + d3 * 128 + (off ^ vk3)), o3);
          __builtin_amdgcn_s_setprio(0);
        }
      };
      pv(p0v, 0);
      pv(p1v, 1);
    };

    loadV(0);
    stageK(0, 0);
    packV(0);
    __syncthreads();

    for (int t = 0; t < nt; ++t) {
      int cur = t & 1, nxt = cur ^ 1;
      bool more = (t + 1) < nt;
      if (more) {
        loadV((t + 1) * 64);
        stageK(nxt, (t + 1) * 64);
      }
      if (t <= lim) tile(t * 64, &Ks[cur][0], &Vs[cur][0]);
      if (more) packV(nxt);
      __syncthreads();
    }

#pragma unroll
    for (int r = 0; r < 16; ++r) {
      int ql = (r & 3) + 8 * (r >> 2) + hi4;
      float ls = __shfl(lsum, ql, 64);
      float inv = 1.0f / ls;
      size_t base = (tokb + chb + wave * 32 + ql) * (size_t)DMODEL + h * HD + qn;
      O[base] = f2bf(o0[r] * inv);
      O[base + 32] = f2bf(o1[r] * inv);
      O[base + 64] = f2bf(o2[r] * inv);
      O[base + 96] = f2bf(o3[r] * inv);
    }
  }
}

extern "C" void kernel_launch(void* const* d_in, const int* in_sizes, int n_in,
                              void* d_out, int out_size, void* d_ws, size_t ws_size,
                              hipStream_t stream) {
  const float* x  = (const float*)d_in[0];
  const float* Wq = (const float*)d_in[1];
  const float* Wk = (const float*)d_in[2];
  const float* Wv = (const float*)d_in[3];
  const float* Wo = (const float*)d_in[4];
  const float* qw = (const float*)d_in[5];
  const float* kw = (const float*)d_in[6];
  float* out = (float*)d_out;

  // Workspace (128 MiB):
  //   [0,   32M)  xb (bf16 x)  -- dead after GEMM1 -> reused as Wot
  //   [32M, 64M)  AO (attn out; region dead after GEMM1)
  //   [32M, 80M)  Wqkvt        -- dead after GEMM1
  //   [80M, 128M) QKVb
  char* ws = (char*)d_ws;
  u16* xb    = (u16*)(ws);
  u16* Wqkvt = (u16*)(ws + 33554432);
  u16* QKVb  = (u16*)(ws + 83886080);
  u16* Wot   = xb;
  u16* AO    = Wqkvt;

  cvt_f32_bf16<<<2048, 256, 0, stream>>>(x, xb, (2 * SEQ * DMODEL) / 4);
  tconv3<<<dim3(96, DMODEL / 64), 256, 0, stream>>>(Wq, Wk, Wv, Wqkvt);

  // gemm1: 128x192 tile -> 1024 blocks = 2 exact generations at 2 blocks/CU
  gemm_db192<u16><<<(4096 / 128) * (QKVN / 192), 256, 0, stream>>>(xb, Wqkvt, QKVb, 4096, QKVN, DMODEL);
  // K-only norm+rope (Q fused into attn)
  normrope_k<<<(4096 * 8) / 4, 256, 0, stream>>>(QKVb, kw);

  tconv<<<dim3(DMODEL / 64, DMODEL / 64), 256, 0, stream>>>(Wo, Wot, DMODEL, 0);
  attn<<<256, 512, 0, stream>>>(QKVb, qw, AO);
  // gemm2: 1024 blocks -> double-buffer template (2 blocks/CU, exactly 2 generations)
  gemm_db<float><<<(4096 / 128) * (DMODEL / 128), 256, 0, stream>>>(AO, Wot, out, 4096, DMODEL, DMODEL);
}

// Round 17
// 563.563 us; speedup vs baseline: 1.9492x; 1.9492x over previous
//
#include <hip/hip_runtime.h>

typedef unsigned short u16;
typedef unsigned int u32;
typedef __attribute__((ext_vector_type(8))) short bf16x8;
typedef __attribute__((ext_vector_type(4))) float f32x4;
typedef __attribute__((ext_vector_type(16))) float f32x16;

#define NH 32
#define NKV 8
#define HD 128
#define SEQ 2048
#define DMODEL 4096
#define QKVN 6144
#define RMS_EPS 1e-6f
#define SM_SCALE 0.08838834764831845f
#define NEG_INF -1e30f

#define AS1 __attribute__((address_space(1)))
#define AS3 __attribute__((address_space(3)))

__device__ __forceinline__ u16 f2bf(float f) {
  unsigned int u = __float_as_uint(f);
  u += 0x7FFFu + ((u >> 16) & 1u);
  return (u16)(u >> 16);
}
__device__ __forceinline__ float bf2f(u16 b) {
  return __uint_as_float(((unsigned int)b) << 16);
}
__device__ __forceinline__ u32 packbf(float lo, float hi) {
  u32 a = __float_as_uint(lo) + 0x8000u;
  u32 b = __float_as_uint(hi) + 0x8000u;
  return __builtin_amdgcn_perm(b, a, 0x07060302u);
}

__device__ __forceinline__ f32x4 mfma16(bf16x8 a, bf16x8 b, f32x4 c) {
  return __builtin_amdgcn_mfma_f32_16x16x32_bf16(a, b, c, 0, 0, 0);
}
__device__ __forceinline__ f32x16 mfma32(bf16x8 a, bf16x8 b, f32x16 c) {
  return __builtin_amdgcn_mfma_f32_32x32x16_bf16(a, b, c, 0, 0, 0);
}

__device__ __forceinline__ void stage16(const u16* g, u16* l) {
  __builtin_amdgcn_global_load_lds((const AS1 u32*)g, (AS3 u32*)l, 16, 0, 0);
}

// ---------------- convert x: f32 -> bf16 ----------------
__global__ __launch_bounds__(256) void cvt_f32_bf16(const float* __restrict__ in,
                                                    u16* __restrict__ out, int n4) {
  int stride = gridDim.x * blockDim.x;
  for (int i = blockIdx.x * blockDim.x + threadIdx.x; i < n4; i += stride) {
    float4 v = ((const float4*)in)[i];
    ushort4 o;
    o.x = f2bf(v.x); o.y = f2bf(v.y); o.z = f2bf(v.z); o.w = f2bf(v.w);
    ((ushort4*)out)[i] = o;
  }
}

// ---------------- transpose-convert, 64x64 tile (r14 proven) ----------------
__device__ __forceinline__ void tconv_tile(const float* __restrict__ W, u16* __restrict__ Wt,
                                           int N, int rowoff, int n0, int k0, int tid) {
  __shared__ float t[64][66];
  int ln = tid & 63;
  int lk = tid >> 6;
#pragma unroll
  for (int i = 0; i < 16; ++i) {
    int kk = lk + i * 4;
    t[ln][kk] = W[(size_t)(k0 + kk) * N + n0 + ln];
  }
  __syncthreads();
  int kc = tid & 31;
  int nr = tid >> 5;
#pragma unroll
  for (int j = 0; j < 8; ++j) {
    int n = nr + j * 8;
    float2 f = *(const float2*)&t[n][kc * 2];
    ushort2 o;
    o.x = f2bf(f.x);
    o.y = f2bf(f.y);
    *(ushort2*)&Wt[(size_t)(rowoff + n0 + n) * DMODEL + k0 + kc * 2] = o;
  }
}

// single kernel for Wq/Wk/Wv (one launch)
__global__ __launch_bounds__(256) void tconv3(const float* __restrict__ Wq,
                                              const float* __restrict__ Wk,
                                              const float* __restrict__ Wv,
                                              u16* __restrict__ Wt) {
  int bx = blockIdx.x, k0 = blockIdx.y * 64, tid = threadIdx.x;
  if (bx < 64)       tconv_tile(Wq, Wt, DMODEL, 0, bx * 64, k0, tid);
  else if (bx < 80)  tconv_tile(Wk, Wt, NKV * HD, DMODEL, (bx - 64) * 64, k0, tid);
  else               tconv_tile(Wv, Wt, NKV * HD, DMODEL + NKV * HD, (bx - 80) * 64, k0, tid);
}

__global__ __launch_bounds__(256) void tconv(const float* __restrict__ W, u16* __restrict__ Wt,
                                             int N, int rowoff) {
  tconv_tile(W, Wt, N, rowoff, blockIdx.x * 64, blockIdx.y * 64, threadIdx.x);
}

__device__ __forceinline__ void storeC(u16* p, float v) { *p = f2bf(v); }
__device__ __forceinline__ void storeC(float* p, float v) { *p = v; }

// ---------------- GEMM db192: 128x192 tile, BK=64, explicit double-buffer (r15 proven) ----
template <typename OutT>
__global__ __launch_bounds__(256, 2) void gemm_db192(const u16* __restrict__ A,
                                                     const u16* __restrict__ Bt,
                                                     OutT* __restrict__ C, int M, int N, int K) {
  __shared__ __align__(16) u16 As[2][128 * 64];
  __shared__ __align__(16) u16 Bs[2][192 * 64];
  int nwg = gridDim.x, q8 = nwg >> 3, bid = blockIdx.x;
  int nid = (bid & 7) * q8 + (bid >> 3);
  int mt = M >> 7;
  int m0 = (nid % mt) * 128, n0 = (nid / mt) * 192;
  int tid = threadIdx.x, wave = tid >> 6, lane = tid & 63;
  int wm = (wave >> 1) * 64, wn = (wave & 1) * 96;
  f32x4 acc[4][6] = {};
  int fr = lane & 15, fq = lane >> 4;

  int srow_ = tid >> 3;
  int scol = ((tid & 7) ^ (srow_ & 7)) * 8;
  const u16* aSrc = A + (size_t)(m0 + srow_) * K + scol;
  const u16* bSrc = Bt + (size_t)(n0 + srow_) * K + scol;
  size_t rstride = (size_t)32 * K;
  int dofs = wave * 512;
  int akey = (fr & 7);

  auto stage = [&](int buf, int kb) {
#pragma unroll
    for (int i = 0; i < 4; ++i)
      stage16(aSrc + i * rstride + kb, &As[buf][0] + i * 2048 + dofs);
#pragma unroll
    for (int i = 0; i < 6; ++i)
      stage16(bSrc + i * rstride + kb, &Bs[buf][0] + i * 2048 + dofs);
  };

  int NT = K >> 6;
  stage(0, 0);
  __syncthreads();
  for (int j = 0; j < NT; ++j) {
    int cur = j & 1;
    if (j + 1 < NT) stage(cur ^ 1, (j + 1) << 6);
    const char* Ab = (const char*)&As[cur][0];
    const char* Bb = (const char*)&Bs[cur][0];
#pragma unroll
    for (int ks = 0; ks < 2; ++ks) {
      bf16x8 af[4], bfv[6];
      int slot = (ks * 4 + fq) ^ akey;
#pragma unroll
      for (int i = 0; i < 4; ++i)
        af[i] = *(const bf16x8*)(Ab + (wm + i * 16 + fr) * 128 + slot * 16);
#pragma unroll
      for (int j2 = 0; j2 < 6; ++j2)
        bfv[j2] = *(const bf16x8*)(Bb + (wn + j2 * 16 + fr) * 128 + slot * 16);
      __builtin_amdgcn_s_setprio(1);
#pragma unroll
      for (int i = 0; i < 4; ++i)
#pragma unroll
        for (int j2 = 0; j2 < 6; ++j2)
          acc[i][j2] = mfma16(af[i], bfv[j2], acc[i][j2]);
      __builtin_amdgcn_s_setprio(0);
    }
    __syncthreads();
  }
#pragma unroll
  for (int i = 0; i < 4; ++i)
#pragma unroll
    for (int j = 0; j < 6; ++j)
#pragma unroll
      for (int r = 0; r < 4; ++r) {
        int row = m0 + wm + i * 16 + fq * 4 + r;
        int col = n0 + wn + j * 16 + fr;
        storeC(&C[(size_t)row * N + col], acc[i][j][r]);
      }
}

// ---------------- GEMM db (r12 proven): 128x128, BK=64, double-buffer ----------------
template <typename OutT>
__global__ __launch_bounds__(256) void gemm_db(const u16* __restrict__ A, const u16* __restrict__ Bt,
                                               OutT* __restrict__ C, int M, int N, int K) {
  __shared__ __align__(16) u16 As[2][128 * 64];
  __shared__ __align__(16) u16 Bs[2][128 * 64];
  int nwg = gridDim.x, q8 = nwg >> 3, bid = blockIdx.x;
  int nid = (bid & 7) * q8 + (bid >> 3);
  int mt = M >> 7;
  int m0 = (nid % mt) * 128, n0 = (nid / mt) * 128;
  int tid = threadIdx.x, wave = tid >> 6, lane = tid & 63;
  int wm = (wave >> 1) * 64, wn = (wave & 1) * 64;
  f32x4 acc[4][4] = {};
  int fr = lane & 15, fq = lane >> 4;

  int srow_ = tid >> 3;
  int scol = ((tid & 7) ^ (srow_ & 7)) * 8;
  const u16* aSrc = A + (size_t)(m0 + srow_) * K + scol;
  const u16* bSrc = Bt + (size_t)(n0 + srow_) * K + scol;
  size_t rstride = (size_t)32 * K;
  int dofs = wave * 512;
  int akey = (fr & 7);

  auto stage = [&](int buf, int kb) {
#pragma unroll
    for (int i = 0; i < 4; ++i) {
      stage16(aSrc + i * rstride + kb, &As[buf][0] + i * 2048 + dofs);
      stage16(bSrc + i * rstride + kb, &Bs[buf][0] + i * 2048 + dofs);
    }
  };

  int NT = K >> 6;
  stage(0, 0);
  __syncthreads();
  for (int j = 0; j < NT; ++j) {
    int cur = j & 1;
    if (j + 1 < NT) stage(cur ^ 1, (j + 1) << 6);
    const char* Ab = (const char*)&As[cur][0];
    const char* Bb = (const char*)&Bs[cur][0];
#pragma unroll
    for (int ks = 0; ks < 2; ++ks) {
      bf16x8 af[4], bfv[4];
      int slot = (ks * 4 + fq) ^ akey;
#pragma unroll
      for (int i = 0; i < 4; ++i)
        af[i] = *(const bf16x8*)(Ab + (wm + i * 16 + fr) * 128 + slot * 16);
#pragma unroll
      for (int j2 = 0; j2 < 4; ++j2)
        bfv[j2] = *(const bf16x8*)(Bb + (wn + j2 * 16 + fr) * 128 + slot * 16);
      __builtin_amdgcn_s_setprio(1);
#pragma unroll
      for (int i = 0; i < 4; ++i)
#pragma unroll
        for (int j2 = 0; j2 < 4; ++j2)
          acc[i][j2] = mfma16(af[i], bfv[j2], acc[i][j2]);
      __builtin_amdgcn_s_setprio(0);
    }
    __syncthreads();
  }
#pragma unroll
  for (int i = 0; i < 4; ++i)
#pragma unroll
    for (int j = 0; j < 4; ++j)
#pragma unroll
      for (int r = 0; r < 4; ++r) {
        int row = m0 + wm + i * 16 + fq * 4 + r;
        int col = n0 + wn + j * 16 + fr;
        storeC(&C[(size_t)row * N + col], acc[i][j][r]);
      }
}

// ---------------- K-only RMSNorm + RoPE (Q fused into attn) ----------------
__global__ __launch_bounds__(256) void normrope_k(u16* __restrict__ QKV,
                                                  const float* __restrict__ kw) {
  int wq = threadIdx.x >> 6, lane = threadIdx.x & 63;
  int gid = blockIdx.x * 4 + wq;  // 0 .. 4096*8-1
  int token = gid >> 3, head = gid & 7;
  int pos = token & (SEQ - 1);
  u16* row = QKV + (size_t)token * QKVN + DMODEL + head * HD;
  ushort2 xv = *(const ushort2*)(row + 2 * lane);
  float x1 = bf2f(xv.x), x2 = bf2f(xv.y);
  float ssq = x1 * x1 + x2 * x2;
#pragma unroll
  for (int o = 32; o; o >>= 1) ssq += __shfl_xor(ssq, o, 64);
  float rms = rsqrtf(ssq * (1.0f / HD) + RMS_EPS);
  float y1 = x1 * rms * kw[2 * lane];
  float y2 = x2 * rms * kw[2 * lane + 1];
  float freq = exp2f((float)lane * -0.20762050593046014f);
  float ang = (float)pos * freq;
  float s, c;
  __sincosf(ang, &s, &c);
  ushort2 ov;
  ov.x = f2bf(y1 * c - y2 * s);
  ov.y = f2bf(y1 * s + y2 * c);
  *(ushort2*)(row + 2 * lane) = ov;
}

// ---------------- 8-wave 32x32 swapped-QK^T flash attention + fused Q norm/rope ----------------
// Q is read RAW from gemm1 output; RMSNorm+RoPE+SM_SCALE applied in-register per pass.
// launch_bounds (512,2): VGPR cap 256 — the (512,4)/128-cap of r16 spilled accumulators
// to scratch (1.6GB traffic, 5x slowdown). K normed by normrope_k beforehand.
__global__ __launch_bounds__(512, 2) void attn(const u16* __restrict__ QKV,
                                               const float* __restrict__ qw,
                                               u16* __restrict__ O) {
  int bid0 = blockIdx.x;
  int bid = (bid0 & 7) * 32 + (bid0 >> 3);
  int pairi = bid & 3, h = (bid >> 2) & 31, b = bid >> 7;
  int tid = threadIdx.x, wave = tid >> 6, lane = tid & 63;
  int qn = lane & 31, hi = lane >> 5;
  int hi4 = hi * 4, hi16 = hi * 16;
  int kvh = h >> 2;

  __shared__ __align__(16) u16 Ks[2][64 * 128];
  __shared__ __align__(16) u16 Vs[2][128 * 64];

  size_t tokb = (size_t)b * SEQ;
  const u16* Kg = QKV + tokb * QKVN + DMODEL + kvh * HD;
  const u16* Vg = Kg + NKV * HD;
  int srow = tid >> 4, sl = tid & 15;

  int kk0 = (qn & 7) << 4;
  int d0 = qn, d1 = 32 + qn, d2 = 64 + qn, d3 = 96 + qn;
  int vk0 = ((d0 ^ (d0 >> 3)) & 7) << 4;
  int vk1 = ((d1 ^ (d1 >> 3)) & 7) << 4;
  int vk2 = ((d2 ^ (d2 >> 3)) & 7) << 4;
  int vk3 = ((d3 ^ (d3 >> 3)) & 7) << 4;

  int4 vreg[2];
  auto loadV = [&](int kv0) {
#pragma unroll
    for (int i = 0; i < 2; ++i)
      vreg[i] = *(const int4*)(Vg + (size_t)(kv0 + i * 32 + srow) * QKVN + sl * 8);
  };
  auto stageK = [&](int buf, int kv0) {
#pragma unroll
    for (int i = 0; i < 2; ++i) {
      int row = i * 32 + srow;
      __builtin_amdgcn_global_load_lds(
          (const AS1 u32*)(Kg + (size_t)(kv0 + row) * QKVN + ((sl ^ (row & 7)) * 8)),
          (AS3 u32*)(&Ks[buf][0] + (i * 32 + wave * 4) * 128), 16, 0, 0);
    }
  };
  auto packV = [&](int buf) {
#pragma unroll
    for (int i = 0; i < 2; ++i) {
      int row = i * 32 + srow;
      int4 dvi = vreg[i];
      int4 dpi;
      dpi.x = __shfl_xor(dvi.x, 16, 64);
      dpi.y = __shfl_xor(dvi.y, 16, 64);
      dpi.z = __shfl_xor(dvi.z, 16, 64);
      dpi.w = __shfl_xor(dvi.w, 16, 64);
      if (((tid >> 4) & 1) == 0) {
        const u16* own = (const u16*)&dvi;
        const u16* par = (const u16*)&dpi;
#pragma unroll
        for (int j = 0; j < 8; ++j) {
          u32 wv = (u32)own[j] | ((u32)par[j] << 16);
          int d = sl * 8 + j;
          int vk = ((d ^ (d >> 3)) & 7) << 4;
          *(u32*)((char*)&Vs[buf][0] + d * 128 + ((2 * row) ^ vk)) = wv;
        }
      }
    }
  };

  for (int pass = 0; pass < 2; ++pass) {
    int chunk = pass ? (7 - pairi) : pairi;
    int chb = chunk * 256;
    int nt = (chunk + 1) * 4;
    int q0w = chb + wave * 32;
    int qabs = q0w + qn;
    int lim = chunk * 4 + (wave >> 1);
    int diag = q0w & ~63;

    // ---- fused Q: raw load -> RMSNorm -> RoPE -> *SM_SCALE, all in-register ----
    bf16x8 qf[8];
    {
      const u16* qp = QKV + (tokb + q0w + qn) * QKVN + h * HD;
      float ssq = 0.f;
#pragma unroll
      for (int d = 0; d < 8; ++d) {
        qf[d] = *(const bf16x8*)(qp + d * 16 + hi * 8);
#pragma unroll
        for (int j = 0; j < 8; ++j) {
          float f = bf2f((u16)qf[d][j]);
          ssq += f * f;
        }
      }
      ssq += __shfl_xor(ssq, 32, 64);
      float rms = rsqrtf(ssq * (1.0f / HD) + RMS_EPS) * SM_SCALE;
      int pos = q0w + qn;
#pragma unroll
      for (int d = 0; d < 8; ++d) {
        const float* wp = qw + d * 16 + hi * 8;
        union { u32 w[4]; bf16x8 v; } uo;
#pragma unroll
        for (int jj = 0; jj < 4; ++jj) {
          float y1 = bf2f((u16)qf[d][2 * jj]) * rms * wp[2 * jj];
          float y2 = bf2f((u16)qf[d][2 * jj + 1]) * rms * wp[2 * jj + 1];
          float fr8 = exp2f((float)(d * 8 + hi * 4 + jj) * -0.20762050593046014f);
          float ang = (float)pos * fr8;
          float s, c;
          __sincosf(ang, &s, &c);
          uo.w[jj] = packbf(y1 * c - y2 * s, y1 * s + y2 * c);
        }
        qf[d] = uo.v;
      }
    }

    f32x16 o0 = {}, o1 = {}, o2 = {}, o3 = {};
    float mrow = NEG_INF, lsum = 0.f;

    auto tile = [&](int kv0, const u16* Kl, const u16* Vl) {
      f32x16 p0v = {}, p1v = {};
      {
        const char* kb0 = (const char*)Kl + qn * 256;
        const char* kb1 = (const char*)Kl + (32 + qn) * 256;
        __builtin_amdgcn_s_setprio(1);
#pragma unroll
        for (int d = 0; d < 8; ++d) {
          bf16x8 k0 = *(const bf16x8*)(kb0 + ((d * 32 + hi16) ^ kk0));
          bf16x8 k1 = *(const bf16x8*)(kb1 + ((d * 32 + hi16) ^ kk0));
          p0v = mfma32(k0, qf[d], p0v);
          p1v = mfma32(k1, qf[d], p1v);
        }
        __builtin_amdgcn_s_setprio(0);
      }
      if (kv0 == diag) {
#pragma unroll
        for (int r = 0; r < 16; ++r) {
          int kva = kv0 + (r & 3) + 8 * (r >> 2) + hi4;
          if (kva > qabs) p0v[r] = NEG_INF;
          if (kva + 32 > qabs) p1v[r] = NEG_INF;
        }
      }
      float tmax = NEG_INF;
#pragma unroll
      for (int r = 0; r < 16; ++r) tmax = fmaxf(tmax, fmaxf(p0v[r], p1v[r]));
      tmax = fmaxf(tmax, __shfl_xor(tmax, 32, 64));
      if (!__all(tmax <= mrow + 8.0f)) {
        float nm = fmaxf(mrow, tmax);
        float corr = __expf(mrow - nm);
        mrow = nm;
        lsum *= corr;
#pragma unroll
        for (int r = 0; r < 16; ++r) {
          int srcl = (r & 3) + 8 * (r >> 2) + hi4;
          float cr = __shfl(corr, srcl, 64);
          o0[r] *= cr; o1[r] *= cr; o2[r] *= cr; o3[r] *= cr;
        }
      }
      float rs = 0.f;
#pragma unroll
      for (int r = 0; r < 16; ++r) {
        p0v[r] = __expf(p0v[r] - mrow);
        p1v[r] = __expf(p1v[r] - mrow);
        rs += p0v[r] + p1v[r];
      }
      rs += __shfl_xor(rs, 32, 64);
      lsum += rs;

      auto pv = [&](const f32x16& pk, int kvs) {
#pragma unroll
        for (int e = 0; e < 2; ++e) {
          u32 A = packbf(pk[e * 8 + 0], pk[e * 8 + 1]);
          u32 Bw = packbf(pk[e * 8 + 2], pk[e * 8 + 3]);
          u32 C = packbf(pk[e * 8 + 4], pk[e * 8 + 5]);
          u32 Dw = packbf(pk[e * 8 + 6], pk[e * 8 + 7]);
          u32 sA = __shfl_xor(A, 32, 64), sC = __shfl_xor(C, 32, 64);
          u32 sB = __shfl_xor(Bw, 32, 64), sD = __shfl_xor(Dw, 32, 64);
          union { u32 w[4]; bf16x8 v; } fr;
          fr.w[0] = hi ? sC : A;
          fr.w[1] = hi ? sD : Bw;
          fr.w[2] = hi ? C : sA;
          fr.w[3] = hi ? Dw : sB;
          int off = (kvs * 2 + e) * 32 + hi16;
          __builtin_amdgcn_s_setprio(1);
          o0 = mfma32(fr.v, *(const bf16x8*)((const char*)Vl + d0 * 128 + (off ^ vk0)), o0);
          o1 = mfma32(fr.v, *(const bf16x8*)((const char*)Vl + d1 * 128 + (off ^ vk1)), o1);
          o2 = mfma32(fr.v, *(const bf16x8*)((const char*)Vl + d2 * 128 + (off ^ vk2)), o2);
          o3 = mfma32(fr.v, *(const bf16x8*)((const char*)Vl + d3 * 128 + (off ^ vk3)), o3);
          __builtin_amdgcn_s_setprio(0);
        }
      };
      pv(p0v, 0);
      pv(p1v, 1);
    };

    loadV(0);
    stageK(0, 0);
    packV(0);
    __syncthreads();

    for (int t = 0; t < nt; ++t) {
      int cur = t & 1, nxt = cur ^ 1;
      bool more = (t + 1) < nt;
      if (more) {
        loadV((t + 1) * 64);
        stageK(nxt, (t + 1) * 64);
      }
      if (t <= lim) tile(t * 64, &Ks[cur][0], &Vs[cur][0]);
      if (more) packV(nxt);
      __syncthreads();
    }

#pragma unroll
    for (int r = 0; r < 16; ++r) {
      int ql = (r & 3) + 8 * (r >> 2) + hi4;
      float ls = __shfl(lsum, ql, 64);
      float inv = 1.0f / ls;
      size_t base = (tokb + chb + wave * 32 + ql) * (size_t)DMODEL + h * HD + qn;
      O[base] = f2bf(o0[r] * inv);
      O[base + 32] = f2bf(o1[r] * inv);
      O[base + 64] = f2bf(o2[r] * inv);
      O[base + 96] = f2bf(o3[r] * inv);
    }
  }
}

extern "C" void kernel_launch(void* const* d_in, const int* in_sizes, int n_in,
                              void* d_out, int out_size, void* d_ws, size_t ws_size,
                              hipStream_t stream) {
  const float* x  = (const float*)d_in[0];
  const float* Wq = (const float*)d_in[1];
  const float* Wk = (const float*)d_in[2];
  const float* Wv = (const float*)d_in[3];
  const float* Wo = (const float*)d_in[4];
  const float* qw = (const float*)d_in[5];
  const float* kw = (const float*)d_in[6];
  float* out = (float*)d_out;

  // Workspace (128 MiB):
  //   [0,   32M)  xb (bf16 x)  -- dead after GEMM1 -> reused as Wot
  //   [32M, 64M)  AO (attn out; region dead after GEMM1)
  //   [32M, 80M)  Wqkvt        -- dead after GEMM1
  //   [80M, 128M) QKVb
  char* ws = (char*)d_ws;
  u16* xb    = (u16*)(ws);
  u16* Wqkvt = (u16*)(ws + 33554432);
  u16* QKVb  = (u16*)(ws + 83886080);
  u16* Wot   = xb;
  u16* AO    = Wqkvt;

  cvt_f32_bf16<<<2048, 256, 0, stream>>>(x, xb, (2 * SEQ * DMODEL) / 4);
  tconv3<<<dim3(96, DMODEL / 64), 256, 0, stream>>>(Wq, Wk, Wv, Wqkvt);

  // gemm1: 128x192 tile -> 1024 blocks = 2 exact generations at 2 blocks/CU
  gemm_db192<u16><<<(4096 / 128) * (QKVN / 192), 256, 0, stream>>>(xb, Wqkvt, QKVb, 4096, QKVN, DMODEL);
  // K-only norm+rope (Q fused into attn)
  normrope_k<<<(4096 * 8) / 4, 256, 0, stream>>>(QKVb, kw);

  tconv<<<dim3(DMODEL / 64, DMODEL / 64), 256, 0, stream>>>(Wo, Wot, DMODEL, 0);
  attn<<<256, 512, 0, stream>>>(QKVb, qw, AO);
  // gemm2: 1024 blocks -> double-buffer template (2 blocks/CU, exactly 2 generations)
  gemm_db<float><<<(4096 / 128) * (DMODEL / 128), 256, 0, stream>>>(AO, Wot, out, 4096, DMODEL, DMODEL);
}

// Round 19
// 552.731 us; speedup vs baseline: 1.9874x; 1.0196x over previous
//
#include <hip/hip_runtime.h>

typedef unsigned short u16;
typedef unsigned int u32;
typedef __attribute__((ext_vector_type(8))) short bf16x8;
typedef __attribute__((ext_vector_type(4))) float f32x4;
typedef __attribute__((ext_vector_type(16))) float f32x16;

#define NH 32
#define NKV 8
#define HD 128
#define SEQ 2048
#define DMODEL 4096
#define QKVN 6144
#define RMS_EPS 1e-6f
#define SM_SCALE 0.08838834764831845f
#define NEG_INF -1e30f

#define AS1 __attribute__((address_space(1)))
#define AS3 __attribute__((address_space(3)))

__device__ __forceinline__ u16 f2bf(float f) {
  unsigned int u = __float_as_uint(f);
  u += 0x7FFFu + ((u >> 16) & 1u);
  return (u16)(u >> 16);
}
__device__ __forceinline__ float bf2f(u16 b) {
  return __uint_as_float(((unsigned int)b) << 16);
}
__device__ __forceinline__ u32 packbf(float lo, float hi) {
  u32 a = __float_as_uint(lo) + 0x8000u;
  u32 b = __float_as_uint(hi) + 0x8000u;
  return __builtin_amdgcn_perm(b, a, 0x07060302u);
}

__device__ __forceinline__ f32x4 mfma16(bf16x8 a, bf16x8 b, f32x4 c) {
  return __builtin_amdgcn_mfma_f32_16x16x32_bf16(a, b, c, 0, 0, 0);
}
__device__ __forceinline__ f32x16 mfma32(bf16x8 a, bf16x8 b, f32x16 c) {
  return __builtin_amdgcn_mfma_f32_32x32x16_bf16(a, b, c, 0, 0, 0);
}

__device__ __forceinline__ void stage16(const u16* g, u16* l) {
  __builtin_amdgcn_global_load_lds((const AS1 u32*)g, (AS3 u32*)l, 16, 0, 0);
}

// ---------------- transpose-convert, 64x64 tile (r14 proven) ----------------
__device__ __forceinline__ void tconv_tile(const float* __restrict__ W, u16* __restrict__ Wt,
                                           int N, int rowoff, int n0, int k0, int tid) {
  __shared__ float t[64][66];
  int ln = tid & 63;
  int lk = tid >> 6;
#pragma unroll
  for (int i = 0; i < 16; ++i) {
    int kk = lk + i * 4;
    t[ln][kk] = W[(size_t)(k0 + kk) * N + n0 + ln];
  }
  __syncthreads();
  int kc = tid & 31;
  int nr = tid >> 5;
#pragma unroll
  for (int j = 0; j < 8; ++j) {
    int n = nr + j * 8;
    float2 f = *(const float2*)&t[n][kc * 2];
    ushort2 o;
    o.x = f2bf(f.x);
    o.y = f2bf(f.y);
    *(ushort2*)&Wt[(size_t)(rowoff + n0 + n) * DMODEL + k0 + kc * 2] = o;
  }
}

// merged prep: blocks 0..2047 convert x->bf16; blocks 2048.. transpose Wq/Wk/Wv
__global__ __launch_bounds__(256) void prep(const float* __restrict__ x, u16* __restrict__ xb,
                                            const float* __restrict__ Wq,
                                            const float* __restrict__ Wk,
                                            const float* __restrict__ Wv,
                                            u16* __restrict__ Wt) {
  int bid = blockIdx.x, tid = threadIdx.x;
  if (bid < 2048) {
    int n4 = (2 * SEQ * DMODEL) / 4;
    int stride = 2048 * 256;
    for (int i = bid * 256 + tid; i < n4; i += stride) {
      float4 v = ((const float4*)x)[i];
      ushort4 o;
      o.x = f2bf(v.x); o.y = f2bf(v.y); o.z = f2bf(v.z); o.w = f2bf(v.w);
      ((ushort4*)xb)[i] = o;
    }
  } else {
    int b2 = bid - 2048;
    int bx = b2 % 96, k0 = (b2 / 96) * 64;
    if (bx < 64)       tconv_tile(Wq, Wt, DMODEL, 0, bx * 64, k0, tid);
    else if (bx < 80)  tconv_tile(Wk, Wt, NKV * HD, DMODEL, (bx - 64) * 64, k0, tid);
    else               tconv_tile(Wv, Wt, NKV * HD, DMODEL + NKV * HD, (bx - 80) * 64, k0, tid);
  }
}

__global__ __launch_bounds__(256) void tconv(const float* __restrict__ W, u16* __restrict__ Wt,
                                             int N, int rowoff) {
  tconv_tile(W, Wt, N, rowoff, blockIdx.x * 64, blockIdx.y * 64, threadIdx.x);
}

__device__ __forceinline__ void storeC(u16* p, float v) { *p = f2bf(v); }
__device__ __forceinline__ void storeC(float* p, float v) { *p = v; }

// ---------------- GEMM db192: 128x192 tile, BK=64, explicit double-buffer (r15 proven) ----
template <typename OutT>
__global__ __launch_bounds__(256, 2) void gemm_db192(const u16* __restrict__ A,
                                                     const u16* __restrict__ Bt,
                                                     OutT* __restrict__ C, int M, int N, int K) {
  __shared__ __align__(16) u16 As[2][128 * 64];
  __shared__ __align__(16) u16 Bs[2][192 * 64];
  int nwg = gridDim.x, q8 = nwg >> 3, bid = blockIdx.x;
  int nid = (bid & 7) * q8 + (bid >> 3);
  int mt = M >> 7;
  int m0 = (nid % mt) * 128, n0 = (nid / mt) * 192;
  int tid = threadIdx.x, wave = tid >> 6, lane = tid & 63;
  int wm = (wave >> 1) * 64, wn = (wave & 1) * 96;
  f32x4 acc[4][6] = {};
  int fr = lane & 15, fq = lane >> 4;

  int srow_ = tid >> 3;
  int scol = ((tid & 7) ^ (srow_ & 7)) * 8;
  const u16* aSrc = A + (size_t)(m0 + srow_) * K + scol;
  const u16* bSrc = Bt + (size_t)(n0 + srow_) * K + scol;
  size_t rstride = (size_t)32 * K;
  int dofs = wave * 512;
  int akey = (fr & 7);

  auto stage = [&](int buf, int kb) {
#pragma unroll
    for (int i = 0; i < 4; ++i)
      stage16(aSrc + i * rstride + kb, &As[buf][0] + i * 2048 + dofs);
#pragma unroll
    for (int i = 0; i < 6; ++i)
      stage16(bSrc + i * rstride + kb, &Bs[buf][0] + i * 2048 + dofs);
  };

  int NT = K >> 6;
  stage(0, 0);
  __syncthreads();
  for (int j = 0; j < NT; ++j) {
    int cur = j & 1;
    if (j + 1 < NT) stage(cur ^ 1, (j + 1) << 6);
    const char* Ab = (const char*)&As[cur][0];
    const char* Bb = (const char*)&Bs[cur][0];
#pragma unroll
    for (int ks = 0; ks < 2; ++ks) {
      bf16x8 af[4], bfv[6];
      int slot = (ks * 4 + fq) ^ akey;
#pragma unroll
      for (int i = 0; i < 4; ++i)
        af[i] = *(const bf16x8*)(Ab + (wm + i * 16 + fr) * 128 + slot * 16);
#pragma unroll
      for (int j2 = 0; j2 < 6; ++j2)
        bfv[j2] = *(const bf16x8*)(Bb + (wn + j2 * 16 + fr) * 128 + slot * 16);
      __builtin_amdgcn_s_setprio(1);
#pragma unroll
      for (int i = 0; i < 4; ++i)
#pragma unroll
        for (int j2 = 0; j2 < 6; ++j2)
          acc[i][j2] = mfma16(af[i], bfv[j2], acc[i][j2]);
      __builtin_amdgcn_s_setprio(0);
    }
    __syncthreads();
  }
#pragma unroll
  for (int i = 0; i < 4; ++i)
#pragma unroll
    for (int j = 0; j < 6; ++j)
#pragma unroll
      for (int r = 0; r < 4; ++r) {
        int row = m0 + wm + i * 16 + fq * 4 + r;
        int col = n0 + wn + j * 16 + fr;
        storeC(&C[(size_t)row * N + col], acc[i][j][r]);
      }
}

// ---------------- GEMM db (r12 proven): 128x128, BK=64, double-buffer ----------------
template <typename OutT>
__global__ __launch_bounds__(256) void gemm_db(const u16* __restrict__ A, const u16* __restrict__ Bt,
                                               OutT* __restrict__ C, int M, int N, int K) {
  __shared__ __align__(16) u16 As[2][128 * 64];
  __shared__ __align__(16) u16 Bs[2][128 * 64];
  int nwg = gridDim.x, q8 = nwg >> 3, bid = blockIdx.x;
  int nid = (bid & 7) * q8 + (bid >> 3);
  int mt = M >> 7;
  int m0 = (nid % mt) * 128, n0 = (nid / mt) * 128;
  int tid = threadIdx.x, wave = tid >> 6, lane = tid & 63;
  int wm = (wave >> 1) * 64, wn = (wave & 1) * 64;
  f32x4 acc[4][4] = {};
  int fr = lane & 15, fq = lane >> 4;

  int srow_ = tid >> 3;
  int scol = ((tid & 7) ^ (srow_ & 7)) * 8;
  const u16* aSrc = A + (size_t)(m0 + srow_) * K + scol;
  const u16* bSrc = Bt + (size_t)(n0 + srow_) * K + scol;
  size_t rstride = (size_t)32 * K;
  int dofs = wave * 512;
  int akey = (fr & 7);

  auto stage = [&](int buf, int kb) {
#pragma unroll
    for (int i = 0; i < 4; ++i) {
      stage16(aSrc + i * rstride + kb, &As[buf][0] + i * 2048 + dofs);
      stage16(bSrc + i * rstride + kb, &Bs[buf][0] + i * 2048 + dofs);
    }
  };

  int NT = K >> 6;
  stage(0, 0);
  __syncthreads();
  for (int j = 0; j < NT; ++j) {
    int cur = j & 1;
    if (j + 1 < NT) stage(cur ^ 1, (j + 1) << 6);
    const char* Ab = (const char*)&As[cur][0];
    const char* Bb = (const char*)&Bs[cur][0];
#pragma unroll
    for (int ks = 0; ks < 2; ++ks) {
      bf16x8 af[4], bfv[4];
      int slot = (ks * 4 + fq) ^ akey;
#pragma unroll
      for (int i = 0; i < 4; ++i)
        af[i] = *(const bf16x8*)(Ab + (wm + i * 16 + fr) * 128 + slot * 16);
#pragma unroll
      for (int j2 = 0; j2 < 4; ++j2)
        bfv[j2] = *(const bf16x8*)(Bb + (wn + j2 * 16 + fr) * 128 + slot * 16);
      __builtin_amdgcn_s_setprio(1);
#pragma unroll
      for (int i = 0; i < 4; ++i)
#pragma unroll
        for (int j2 = 0; j2 < 4; ++j2)
          acc[i][j2] = mfma16(af[i], bfv[j2], acc[i][j2]);
      __builtin_amdgcn_s_setprio(0);
    }
    __syncthreads();
  }
#pragma unroll
  for (int i = 0; i < 4; ++i)
#pragma unroll
    for (int j = 0; j < 4; ++j)
#pragma unroll
      for (int r = 0; r < 4; ++r) {
        int row = m0 + wm + i * 16 + fq * 4 + r;
        int col = n0 + wn + j * 16 + fr;
        storeC(&C[(size_t)row * N + col], acc[i][j][r]);
      }
}

// ---------------- RMSNorm + RoPE (Q pre-scaled by SM_SCALE; fast trig) — r15 proven ----------------
__global__ __launch_bounds__(256) void normrope(u16* __restrict__ QKV,
                                                const float* __restrict__ qw,
                                                const float* __restrict__ kw) {
  int wq = threadIdx.x >> 6, lane = threadIdx.x & 63;
  int gid = blockIdx.x * 4 + wq;
  int token = gid / 40, head = gid % 40;
  int pos = token & (SEQ - 1);
  const float* wrow;
  int col;
  float sc;
  if (head < NH) { wrow = qw; col = head * HD; sc = SM_SCALE; }
  else           { wrow = kw; col = DMODEL + (head - NH) * HD; sc = 1.0f; }
  u16* row = QKV + (size_t)token * QKVN + col;
  ushort2 xv = *(const ushort2*)(row + 2 * lane);
  float x1 = bf2f(xv.x), x2 = bf2f(xv.y);
  float ssq = x1 * x1 + x2 * x2;
#pragma unroll
  for (int o = 32; o; o >>= 1) ssq += __shfl_xor(ssq, o, 64);
  float rms = rsqrtf(ssq * (1.0f / HD) + RMS_EPS);
  float y1 = x1 * rms * wrow[2 * lane] * sc;
  float y2 = x2 * rms * wrow[2 * lane + 1] * sc;
  float freq = exp2f((float)lane * -0.20762050593046014f);
  float ang = (float)pos * freq;
  float s, c;
  __sincosf(ang, &s, &c);
  ushort2 ov;
  ov.x = f2bf(y1 * c - y2 * s);
  ov.y = f2bf(y1 * s + y2 * c);
  *(ushort2*)(row + 2 * lane) = ov;
}

// ---------------- 8-wave 32x32 swapped-QK^T flash attention (r15 proven, gated packV) ----------------
__global__ __launch_bounds__(512, 2) void attn(const u16* __restrict__ QKV, u16* __restrict__ O) {
  int bid0 = blockIdx.x;
  int bid = (bid0 & 7) * 32 + (bid0 >> 3);
  int pairi = bid & 3, h = (bid >> 2) & 31, b = bid >> 7;
  int tid = threadIdx.x, wave = tid >> 6, lane = tid & 63;
  int qn = lane & 31, hi = lane >> 5;
  int hi4 = hi * 4, hi16 = hi * 16;
  int kvh = h >> 2;

  __shared__ __align__(16) u16 Ks[2][64 * 128];
  __shared__ __align__(16) u16 Vs[2][128 * 64];

  size_t tokb = (size_t)b * SEQ;
  const u16* Kg = QKV + tokb * QKVN + DMODEL + kvh * HD;
  const u16* Vg = Kg + NKV * HD;
  int srow = tid >> 4, sl = tid & 15;

  int kk0 = (qn & 7) << 4;
  int d0 = qn, d1 = 32 + qn, d2 = 64 + qn, d3 = 96 + qn;
  int vk0 = ((d0 ^ (d0 >> 3)) & 7) << 4;
  int vk1 = ((d1 ^ (d1 >> 3)) & 7) << 4;
  int vk2 = ((d2 ^ (d2 >> 3)) & 7) << 4;
  int vk3 = ((d3 ^ (d3 >> 3)) & 7) << 4;

  int4 vreg[2];
  auto loadV = [&](int kv0) {
#pragma unroll
    for (int i = 0; i < 2; ++i)
      vreg[i] = *(const int4*)(Vg + (size_t)(kv0 + i * 32 + srow) * QKVN + sl * 8);
  };
  auto stageK = [&](int buf, int kv0) {
#pragma unroll
    for (int i = 0; i < 2; ++i) {
      int row = i * 32 + srow;
      __builtin_amdgcn_global_load_lds(
          (const AS1 u32*)(Kg + (size_t)(kv0 + row) * QKVN + ((sl ^ (row & 7)) * 8)),
          (AS3 u32*)(&Ks[buf][0] + (i * 32 + wave * 4) * 128), 16, 0, 0);
    }
  };
  // gated packV (r15 proven): even-srow threads write (kv, kv+1) word pairs
  auto packV = [&](int buf) {
#pragma unroll
    for (int i = 0; i < 2; ++i) {
      int row = i * 32 + srow;
      int4 dvi = vreg[i];
      int4 dpi;
      dpi.x = __shfl_xor(dvi.x, 16, 64);
      dpi.y = __shfl_xor(dvi.y, 16, 64);
      dpi.z = __shfl_xor(dvi.z, 16, 64);
      dpi.w = __shfl_xor(dvi.w, 16, 64);
      if (((tid >> 4) & 1) == 0) {
        const u16* own = (const u16*)&dvi;
        const u16* par = (const u16*)&dpi;
#pragma unroll
        for (int j = 0; j < 8; ++j) {
          u32 wv = (u32)own[j] | ((u32)par[j] << 16);
          int d = sl * 8 + j;
          int vk = ((d ^ (d >> 3)) & 7) << 4;
          *(u32*)((char*)&Vs[buf][0] + d * 128 + ((2 * row) ^ vk)) = wv;
        }
      }
    }
  };

  for (int pass = 0; pass < 2; ++pass) {
    int chunk = pass ? (7 - pairi) : pairi;
    int chb = chunk * 256;
    int nt = (chunk + 1) * 4;
    int q0w = chb + wave * 32;
    int qabs = q0w + qn;
    int lim = chunk * 4 + (wave >> 1);
    int diag = q0w & ~63;

    bf16x8 qf[8];
    {
      const u16* qp = QKV + (tokb + q0w + qn) * QKVN + h * HD;
#pragma unroll
      for (int d = 0; d < 8; ++d) qf[d] = *(const bf16x8*)(qp + d * 16 + hi * 8);
    }

    f32x16 o0 = {}, o1 = {}, o2 = {}, o3 = {};
    float mrow = NEG_INF, lsum = 0.f;

    auto tile = [&](int kv0, const u16* Kl, const u16* Vl) {
      f32x16 p0v = {}, p1v = {};
      {
        const char* kb0 = (const char*)Kl + qn * 256;
        const char* kb1 = (const char*)Kl + (32 + qn) * 256;
        __builtin_amdgcn_s_setprio(1);
#pragma unroll
        for (int d = 0; d < 8; ++d) {
          bf16x8 k0 = *(const bf16x8*)(kb0 + ((d * 32 + hi16) ^ kk0));
          bf16x8 k1 = *(const bf16x8*)(kb1 + ((d * 32 + hi16) ^ kk0));
          p0v = mfma32(k0, qf[d], p0v);
          p1v = mfma32(k1, qf[d], p1v);
        }
        __builtin_amdgcn_s_setprio(0);
      }
      if (kv0 == diag) {
#pragma unroll
        for (int r = 0; r < 16; ++r) {
          int kva = kv0 + (r & 3) + 8 * (r >> 2) + hi4;
          if (kva > qabs) p0v[r] = NEG_INF;
          if (kva + 32 > qabs) p1v[r] = NEG_INF;
        }
      }
      float tmax = NEG_INF;
#pragma unroll
      for (int r = 0; r < 16; ++r) tmax = fmaxf(tmax, fmaxf(p0v[r], p1v[r]));
      tmax = fmaxf(tmax, __shfl_xor(tmax, 32, 64));
      if (!__all(tmax <= mrow + 8.0f)) {
        float nm = fmaxf(mrow, tmax);
        float corr = __expf(mrow - nm);
        mrow = nm;
        lsum *= corr;
#pragma unroll
        for (int r = 0; r < 16; ++r) {
          int srcl = (r & 3) + 8 * (r >> 2) + hi4;
          float cr = __shfl(corr, srcl, 64);
          o0[r] *= cr; o1[r] *= cr; o2[r] *= cr; o3[r] *= cr;
        }
      }
      float rs = 0.f;
#pragma unroll
      for (int r = 0; r < 16; ++r) {
        p0v[r] = __expf(p0v[r] - mrow);
        p1v[r] = __expf(p1v[r] - mrow);
        rs += p0v[r] + p1v[r];
      }
      rs += __shfl_xor(rs, 32, 64);
      lsum += rs;

      auto pv = [&](const f32x16& pk, int kvs) {
#pragma unroll
        for (int e = 0; e < 2; ++e) {
          u32 A = packbf(pk[e * 8 + 0], pk[e * 8 + 1]);
          u32 Bw = packbf(pk[e * 8 + 2], pk[e * 8 + 3]);
          u32 C = packbf(pk[e * 8 + 4], pk[e * 8 + 5]);
          u32 Dw = packbf(pk[e * 8 + 6], pk[e * 8 + 7]);
          u32 sA = __shfl_xor(A, 32, 64), sC = __shfl_xor(C, 32, 64);
          u32 sB = __shfl_xor(Bw, 32, 64), sD = __shfl_xor(Dw, 32, 64);
          union { u32 w[4]; bf16x8 v; } fr;
          fr.w[0] = hi ? sC : A;
          fr.w[1] = hi ? sD : Bw;
          fr.w[2] = hi ? C : sA;
          fr.w[3] = hi ? Dw : sB;
          int off = (kvs * 2 + e) * 32 + hi16;
          __builtin_amdgcn_s_setprio(1);
          o0 = mfma32(fr.v, *(const bf16x8*)((const char*)Vl + d0 * 128 + (off ^ vk0)), o0);
          o1 = mfma32(fr.v, *(const bf16x8*)((const char*)Vl + d1 * 128 + (off ^ vk1)), o1);
          o2 = mfma32(fr.v, *(const bf16x8*)((const char*)Vl + d2 * 128 + (off ^ vk2)), o2);
          o3 = mfma32(fr.v, *(const bf16x8*)((const char*)Vl + d3 * 128 + (off ^ vk3)), o3);
          __builtin_amdgcn_s_setprio(0);
        }
      };
      pv(p0v, 0);
      pv(p1v, 1);
    };

    loadV(0);
    stageK(0, 0);
    packV(0);
    __syncthreads();

    for (int t = 0; t < nt; ++t) {
      int cur = t & 1, nxt = cur ^ 1;
      bool more = (t + 1) < nt;
      if (more) {
        loadV((t + 1) * 64);
        stageK(nxt, (t + 1) * 64);
      }
      if (t <= lim) tile(t * 64, &Ks[cur][0], &Vs[cur][0]);
      if (more) packV(nxt);
      __syncthreads();
    }

#pragma unroll
    for (int r = 0; r < 16; ++r) {
      int ql = (r & 3) + 8 * (r >> 2) + hi4;
      float ls = __shfl(lsum, ql, 64);
      float inv = 1.0f / ls;
      size_t base = (tokb + chb + wave * 32 + ql) * (size_t)DMODEL + h * HD + qn;
      O[base] = f2bf(o0[r] * inv);
      O[base + 32] = f2bf(o1[r] * inv);
      O[base + 64] = f2bf(o2[r] * inv);
      O[base + 96] = f2bf(o3[r] * inv);
    }
  }
}

extern "C" void kernel_launch(void* const* d_in, const int* in_sizes, int n_in,
                              void* d_out, int out_size, void* d_ws, size_t ws_size,
                              hipStream_t stream) {
  const float* x  = (const float*)d_in[0];
  const float* Wq = (const float*)d_in[1];
  const float* Wk = (const float*)d_in[2];
  const float* Wv = (const float*)d_in[3];
  const float* Wo = (const float*)d_in[4];
  const float* qw = (const float*)d_in[5];
  const float* kw = (const float*)d_in[6];
  float* out = (float*)d_out;

  // Workspace (128 MiB):
  //   [0,   32M)  xb (bf16 x)  -- dead after GEMM1 -> reused as Wot
  //   [32M, 64M)  AO (attn out; region dead after GEMM1)
  //   [32M, 80M)  Wqkvt        -- dead after GEMM1
  //   [80M, 128M) QKVb
  char* ws = (char*)d_ws;
  u16* xb    = (u16*)(ws);
  u16* Wqkvt = (u16*)(ws + 33554432);
  u16* QKVb  = (u16*)(ws + 83886080);
  u16* Wot   = xb;
  u16* AO    = Wqkvt;

  // merged cvt + Wq/Wk/Wv transpose: 2048 + 96*64 = 8192 blocks
  prep<<<2048 + 96 * (DMODEL / 64), 256, 0, stream>>>(x, xb, Wq, Wk, Wv, Wqkvt);

  // gemm1: 128x192 tile -> 1024 blocks = 2 exact generations at 2 blocks/CU
  gemm_db192<u16><<<(4096 / 128) * (QKVN / 192), 256, 0, stream>>>(xb, Wqkvt, QKVb, 4096, QKVN, DMODEL);
  normrope<<<(4096 * 40) / 4, 256, 0, stream>>>(QKVb, qw, kw);

  tconv<<<dim3(DMODEL / 64, DMODEL / 64), 256, 0, stream>>>(Wo, Wot, DMODEL, 0);
  attn<<<256, 512, 0, stream>>>(QKVb, AO);
  // gemm2: 1024 blocks -> double-buffer template (2 blocks/CU, exactly 2 generations)
  gemm_db<float><<<(4096 / 128) * (DMODEL / 128), 256, 0, stream>>>(AO, Wot, out, 4096, DMODEL, DMODEL);
}

// Round 21
// 548.804 us; speedup vs baseline: 2.0016x; 1.0072x over previous
//
#include <hip/hip_runtime.h>

typedef unsigned short u16;
typedef unsigned int u32;
typedef __attribute__((ext_vector_type(8))) short bf16x8;
typedef __attribute__((ext_vector_type(4))) float f32x4;
typedef __attribute__((ext_vector_type(16))) float f32x16;

#define NH 32
#define NKV 8
#define HD 128
#define SEQ 2048
#define DMODEL 4096
#define QKVN 6144
#define RMS_EPS 1e-6f
#define SM_SCALE 0.08838834764831845f
#define NEG_INF -1e30f

#define AS1 __attribute__((address_space(1)))
#define AS3 __attribute__((address_space(3)))

__device__ __forceinline__ u16 f2bf(float f) {
  unsigned int u = __float_as_uint(f);
  u += 0x7FFFu + ((u >> 16) & 1u);
  return (u16)(u >> 16);
}
__device__ __forceinline__ float bf2f(u16 b) {
  return __uint_as_float(((unsigned int)b) << 16);
}
__device__ __forceinline__ u32 packbf(float lo, float hi) {
  u32 a = __float_as_uint(lo) + 0x8000u;
  u32 b = __float_as_uint(hi) + 0x8000u;
  return __builtin_amdgcn_perm(b, a, 0x07060302u);
}

__device__ __forceinline__ f32x4 mfma16(bf16x8 a, bf16x8 b, f32x4 c) {
  return __builtin_amdgcn_mfma_f32_16x16x32_bf16(a, b, c, 0, 0, 0);
}
__device__ __forceinline__ f32x16 mfma32(bf16x8 a, bf16x8 b, f32x16 c) {
  return __builtin_amdgcn_mfma_f32_32x32x16_bf16(a, b, c, 0, 0, 0);
}

__device__ __forceinline__ void stage16(const u16* g, u16* l) {
  __builtin_amdgcn_global_load_lds((const AS1 u32*)g, (AS3 u32*)l, 16, 0, 0);
}

// ---------------- transpose-convert, 64x64 tile (r14 proven) ----------------
__device__ __forceinline__ void tconv_tile(const float* __restrict__ W, u16* __restrict__ Wt,
                                           int N, int rowoff, int n0, int k0, int tid) {
  __shared__ float t[64][66];
  int ln = tid & 63;
  int lk = tid >> 6;
#pragma unroll
  for (int i = 0; i < 16; ++i) {
    int kk = lk + i * 4;
    t[ln][kk] = W[(size_t)(k0 + kk) * N + n0 + ln];
  }
  __syncthreads();
  int kc = tid & 31;
  int nr = tid >> 5;
#pragma unroll
  for (int j = 0; j < 8; ++j) {
    int n = nr + j * 8;
    float2 f = *(const float2*)&t[n][kc * 2];
    ushort2 o;
    o.x = f2bf(f.x);
    o.y = f2bf(f.y);
    *(ushort2*)&Wt[(size_t)(rowoff + n0 + n) * DMODEL + k0 + kc * 2] = o;
  }
}

// merged prep: blocks 0..2047 convert x->bf16; blocks 2048.. transpose Wq/Wk/Wv
__global__ __launch_bounds__(256) void prep(const float* __restrict__ x, u16* __restrict__ xb,
                                            const float* __restrict__ Wq,
                                            const float* __restrict__ Wk,
                                            const float* __restrict__ Wv,
                                            u16* __restrict__ Wt) {
  int bid = blockIdx.x, tid = threadIdx.x;
  if (bid < 2048) {
    int n4 = (2 * SEQ * DMODEL) / 4;
    int stride = 2048 * 256;
    for (int i = bid * 256 + tid; i < n4; i += stride) {
      float4 v = ((const float4*)x)[i];
      ushort4 o;
      o.x = f2bf(v.x); o.y = f2bf(v.y); o.z = f2bf(v.z); o.w = f2bf(v.w);
      ((ushort4*)xb)[i] = o;
    }
  } else {
    int b2 = bid - 2048;
    int bx = b2 % 96, k0 = (b2 / 96) * 64;
    if (bx < 64)       tconv_tile(Wq, Wt, DMODEL, 0, bx * 64, k0, tid);
    else if (bx < 80)  tconv_tile(Wk, Wt, NKV * HD, DMODEL, (bx - 64) * 64, k0, tid);
    else               tconv_tile(Wv, Wt, NKV * HD, DMODEL + NKV * HD, (bx - 80) * 64, k0, tid);
  }
}

__device__ __forceinline__ void storeC(u16* p, float v) { *p = f2bf(v); }
__device__ __forceinline__ void storeC(float* p, float v) { *p = v; }

// ---------------- GEMM db192: 128x192 tile, BK=64, explicit double-buffer (r15 proven) ----
template <typename OutT>
__global__ __launch_bounds__(256, 2) void gemm_db192(const u16* __restrict__ A,
                                                     const u16* __restrict__ Bt,
                                                     OutT* __restrict__ C, int M, int N, int K) {
  __shared__ __align__(16) u16 As[2][128 * 64];
  __shared__ __align__(16) u16 Bs[2][192 * 64];
  int nwg = gridDim.x, q8 = nwg >> 3, bid = blockIdx.x;
  int nid = (bid & 7) * q8 + (bid >> 3);
  int mt = M >> 7;
  int m0 = (nid % mt) * 128, n0 = (nid / mt) * 192;
  int tid = threadIdx.x, wave = tid >> 6, lane = tid & 63;
  int wm = (wave >> 1) * 64, wn = (wave & 1) * 96;
  f32x4 acc[4][6] = {};
  int fr = lane & 15, fq = lane >> 4;

  int srow_ = tid >> 3;
  int scol = ((tid & 7) ^ (srow_ & 7)) * 8;
  const u16* aSrc = A + (size_t)(m0 + srow_) * K + scol;
  const u16* bSrc = Bt + (size_t)(n0 + srow_) * K + scol;
  size_t rstride = (size_t)32 * K;
  int dofs = wave * 512;
  int akey = (fr & 7);

  auto stage = [&](int buf, int kb) {
#pragma unroll
    for (int i = 0; i < 4; ++i)
      stage16(aSrc + i * rstride + kb, &As[buf][0] + i * 2048 + dofs);
#pragma unroll
    for (int i = 0; i < 6; ++i)
      stage16(bSrc + i * rstride + kb, &Bs[buf][0] + i * 2048 + dofs);
  };

  int NT = K >> 6;
  stage(0, 0);
  __syncthreads();
  for (int j = 0; j < NT; ++j) {
    int cur = j & 1;
    if (j + 1 < NT) stage(cur ^ 1, (j + 1) << 6);
    const char* Ab = (const char*)&As[cur][0];
    const char* Bb = (const char*)&Bs[cur][0];
#pragma unroll
    for (int ks = 0; ks < 2; ++ks) {
      bf16x8 af[4], bfv[6];
      int slot = (ks * 4 + fq) ^ akey;
#pragma unroll
      for (int i = 0; i < 4; ++i)
        af[i] = *(const bf16x8*)(Ab + (wm + i * 16 + fr) * 128 + slot * 16);
#pragma unroll
      for (int j2 = 0; j2 < 6; ++j2)
        bfv[j2] = *(const bf16x8*)(Bb + (wn + j2 * 16 + fr) * 128 + slot * 16);
      __builtin_amdgcn_s_setprio(1);
#pragma unroll
      for (int i = 0; i < 4; ++i)
#pragma unroll
        for (int j2 = 0; j2 < 6; ++j2)
          acc[i][j2] = mfma16(af[i], bfv[j2], acc[i][j2]);
      __builtin_amdgcn_s_setprio(0);
    }
    __syncthreads();
  }
#pragma unroll
  for (int i = 0; i < 4; ++i)
#pragma unroll
    for (int j = 0; j < 6; ++j)
#pragma unroll
      for (int r = 0; r < 4; ++r) {
        int row = m0 + wm + i * 16 + fq * 4 + r;
        int col = n0 + wn + j * 16 + fr;
        storeC(&C[(size_t)row * N + col], acc[i][j][r]);
      }
}

// ---------------- GEMM db (r12 proven): 128x128, BK=64, double-buffer ----------------
template <typename OutT>
__global__ __launch_bounds__(256) void gemm_db(const u16* __restrict__ A, const u16* __restrict__ Bt,
                                               OutT* __restrict__ C, int M, int N, int K) {
  __shared__ __align__(16) u16 As[2][128 * 64];
  __shared__ __align__(16) u16 Bs[2][128 * 64];
  int nwg = gridDim.x, q8 = nwg >> 3, bid = blockIdx.x;
  int nid = (bid & 7) * q8 + (bid >> 3);
  int mt = M >> 7;
  int m0 = (nid % mt) * 128, n0 = (nid / mt) * 128;
  int tid = threadIdx.x, wave = tid >> 6, lane = tid & 63;
  int wm = (wave >> 1) * 64, wn = (wave & 1) * 64;
  f32x4 acc[4][4] = {};
  int fr = lane & 15, fq = lane >> 4;

  int srow_ = tid >> 3;
  int scol = ((tid & 7) ^ (srow_ & 7)) * 8;
  const u16* aSrc = A + (size_t)(m0 + srow_) * K + scol;
  const u16* bSrc = Bt + (size_t)(n0 + srow_) * K + scol;
  size_t rstride = (size_t)32 * K;
  int dofs = wave * 512;
  int akey = (fr & 7);

  auto stage = [&](int buf, int kb) {
#pragma unroll
    for (int i = 0; i < 4; ++i) {
      stage16(aSrc + i * rstride + kb, &As[buf][0] + i * 2048 + dofs);
      stage16(bSrc + i * rstride + kb, &Bs[buf][0] + i * 2048 + dofs);
    }
  };

  int NT = K >> 6;
  stage(0, 0);
  __syncthreads();
  for (int j = 0; j < NT; ++j) {
    int cur = j & 1;
    if (j + 1 < NT) stage(cur ^ 1, (j + 1) << 6);
    const char* Ab = (const char*)&As[cur][0];
    const char* Bb = (const char*)&Bs[cur][0];
#pragma unroll
    for (int ks = 0; ks < 2; ++ks) {
      bf16x8 af[4], bfv[4];
      int slot = (ks * 4 + fq) ^ akey;
#pragma unroll
      for (int i = 0; i < 4; ++i)
        af[i] = *(const bf16x8*)(Ab + (wm + i * 16 + fr) * 128 + slot * 16);
#pragma unroll
      for (int j2 = 0; j2 < 4; ++j2)
        bfv[j2] = *(const bf16x8*)(Bb + (wn + j2 * 16 + fr) * 128 + slot * 16);
      __builtin_amdgcn_s_setprio(1);
#pragma unroll
      for (int i = 0; i < 4; ++i)
#pragma unroll
        for (int j2 = 0; j2 < 4; ++j2)
          acc[i][j2] = mfma16(af[i], bfv[j2], acc[i][j2]);
      __builtin_amdgcn_s_setprio(0);
    }
    __syncthreads();
  }
#pragma unroll
  for (int i = 0; i < 4; ++i)
#pragma unroll
    for (int j = 0; j < 4; ++j)
#pragma unroll
      for (int r = 0; r < 4; ++r) {
        int row = m0 + wm + i * 16 + fq * 4 + r;
        int col = n0 + wn + j * 16 + fr;
        storeC(&C[(size_t)row * N + col], acc[i][j][r]);
      }
}

// ---------------- post1: normrope (blocks < 40960) + Wo transpose (blocks >= 40960) ----------------
// FIX vs r20: normrope region is (4096 tokens * 40 heads) / 4 waves = 40960 blocks (was 10240,
// which left 3/4 of tokens un-normed -> absmax 4.91).
__global__ __launch_bounds__(256) void post1(u16* __restrict__ QKV,
                                             const float* __restrict__ qw,
                                             const float* __restrict__ kw,
                                             const float* __restrict__ Wo,
                                             u16* __restrict__ Wot) {
  int bid = blockIdx.x, tid = threadIdx.x;
  if (bid < 40960) {
    int wq = tid >> 6, lane = tid & 63;
    int gid = bid * 4 + wq;
    int token = gid / 40, head = gid % 40;
    int pos = token & (SEQ - 1);
    const float* wrow;
    int col;
    float sc;
    if (head < NH) { wrow = qw; col = head * HD; sc = SM_SCALE; }
    else           { wrow = kw; col = DMODEL + (head - NH) * HD; sc = 1.0f; }
    u16* row = QKV + (size_t)token * QKVN + col;
    ushort2 xv = *(const ushort2*)(row + 2 * lane);
    float x1 = bf2f(xv.x), x2 = bf2f(xv.y);
    float ssq = x1 * x1 + x2 * x2;
#pragma unroll
    for (int o = 32; o; o >>= 1) ssq += __shfl_xor(ssq, o, 64);
    float rms = rsqrtf(ssq * (1.0f / HD) + RMS_EPS);
    float y1 = x1 * rms * wrow[2 * lane] * sc;
    float y2 = x2 * rms * wrow[2 * lane + 1] * sc;
    float freq = exp2f((float)lane * -0.20762050593046014f);
    float ang = (float)pos * freq;
    float s, c;
    __sincosf(ang, &s, &c);
    ushort2 ov;
    ov.x = f2bf(y1 * c - y2 * s);
    ov.y = f2bf(y1 * s + y2 * c);
    *(ushort2*)(row + 2 * lane) = ov;
  } else {
    int b2 = bid - 40960;
    int bx = b2 & 63, k0 = (b2 >> 6) * 64;
    tconv_tile(Wo, Wot, DMODEL, 0, bx * 64, k0, tid);
  }
}

// ---------------- 8-wave 32x32 swapped-QK^T flash attention (r15/r19 proven, gated packV) ----------------
__global__ __launch_bounds__(512, 2) void attn(const u16* __restrict__ QKV, u16* __restrict__ O) {
  int bid0 = blockIdx.x;
  int bid = (bid0 & 7) * 32 + (bid0 >> 3);
  int pairi = bid & 3, h = (bid >> 2) & 31, b = bid >> 7;
  int tid = threadIdx.x, wave = tid >> 6, lane = tid & 63;
  int qn = lane & 31, hi = lane >> 5;
  int hi4 = hi * 4, hi16 = hi * 16;
  int kvh = h >> 2;

  __shared__ __align__(16) u16 Ks[2][64 * 128];
  __shared__ __align__(16) u16 Vs[2][128 * 64];

  size_t tokb = (size_t)b * SEQ;
  const u16* Kg = QKV + tokb * QKVN + DMODEL + kvh * HD;
  const u16* Vg = Kg + NKV * HD;
  int srow = tid >> 4, sl = tid & 15;

  int kk0 = (qn & 7) << 4;
  int d0 = qn, d1 = 32 + qn, d2 = 64 + qn, d3 = 96 + qn;
  int vk0 = ((d0 ^ (d0 >> 3)) & 7) << 4;
  int vk1 = ((d1 ^ (d1 >> 3)) & 7) << 4;
  int vk2 = ((d2 ^ (d2 >> 3)) & 7) << 4;
  int vk3 = ((d3 ^ (d3 >> 3)) & 7) << 4;

  int4 vreg[2];
  auto loadV = [&](int kv0) {
#pragma unroll
    for (int i = 0; i < 2; ++i)
      vreg[i] = *(const int4*)(Vg + (size_t)(kv0 + i * 32 + srow) * QKVN + sl * 8);
  };
  auto stageK = [&](int buf, int kv0) {
#pragma unroll
    for (int i = 0; i < 2; ++i) {
      int row = i * 32 + srow;
      __builtin_amdgcn_global_load_lds(
          (const AS1 u32*)(Kg + (size_t)(kv0 + row) * QKVN + ((sl ^ (row & 7)) * 8)),
          (AS3 u32*)(&Ks[buf][0] + (i * 32 + wave * 4) * 128), 16, 0, 0);
    }
  };
  // gated packV (proven): even-srow threads write (kv, kv+1) word pairs
  auto packV = [&](int buf) {
#pragma unroll
    for (int i = 0; i < 2; ++i) {
      int row = i * 32 + srow;
      int4 dvi = vreg[i];
      int4 dpi;
      dpi.x = __shfl_xor(dvi.x, 16, 64);
      dpi.y = __shfl_xor(dvi.y, 16, 64);
      dpi.z = __shfl_xor(dvi.z, 16, 64);
      dpi.w = __shfl_xor(dvi.w, 16, 64);
      if (((tid >> 4) & 1) == 0) {
        const u16* own = (const u16*)&dvi;
        const u16* par = (const u16*)&dpi;
#pragma unroll
        for (int j = 0; j < 8; ++j) {
          u32 wv = (u32)own[j] | ((u32)par[j] << 16);
          int d = sl * 8 + j;
          int vk = ((d ^ (d >> 3)) & 7) << 4;
          *(u32*)((char*)&Vs[buf][0] + d * 128 + ((2 * row) ^ vk)) = wv;
        }
      }
    }
  };

  for (int pass = 0; pass < 2; ++pass) {
    int chunk = pass ? (7 - pairi) : pairi;
    int chb = chunk * 256;
    int nt = (chunk + 1) * 4;
    int q0w = chb + wave * 32;
    int qabs = q0w + qn;
    int lim = chunk * 4 + (wave >> 1);
    int diag = q0w & ~63;

    bf16x8 qf[8];
    {
      const u16* qp = QKV + (tokb + q0w + qn) * QKVN + h * HD;
#pragma unroll
      for (int d = 0; d < 8; ++d) qf[d] = *(const bf16x8*)(qp + d * 16 + hi * 8);
    }

    f32x16 o0 = {}, o1 = {}, o2 = {}, o3 = {};
    float mrow = NEG_INF, lsum = 0.f;

    auto tile = [&](int kv0, const u16* Kl, const u16* Vl) {
      f32x16 p0v = {}, p1v = {};
      {
        const char* kb0 = (const char*)Kl + qn * 256;
        const char* kb1 = (const char*)Kl + (32 + qn) * 256;
        __builtin_amdgcn_s_setprio(1);
#pragma unroll
        for (int d = 0; d < 8; ++d) {
          bf16x8 k0 = *(const bf16x8*)(kb0 + ((d * 32 + hi16) ^ kk0));
          bf16x8 k1 = *(const bf16x8*)(kb1 + ((d * 32 + hi16) ^ kk0));
          p0v = mfma32(k0, qf[d], p0v);
          p1v = mfma32(k1, qf[d], p1v);
        }
        __builtin_amdgcn_s_setprio(0);
      }
      if (kv0 == diag) {
#pragma unroll
        for (int r = 0; r < 16; ++r) {
          int kva = kv0 + (r & 3) + 8 * (r >> 2) + hi4;
          if (kva > qabs) p0v[r] = NEG_INF;
          if (kva + 32 > qabs) p1v[r] = NEG_INF;
        }
      }
      float tmax = NEG_INF;
#pragma unroll
      for (int r = 0; r < 16; ++r) tmax = fmaxf(tmax, fmaxf(p0v[r], p1v[r]));
      tmax = fmaxf(tmax, __shfl_xor(tmax, 32, 64));
      if (!__all(tmax <= mrow + 8.0f)) {
        float nm = fmaxf(mrow, tmax);
        float corr = __expf(mrow - nm);
        mrow = nm;
        lsum *= corr;
#pragma unroll
        for (int r = 0; r < 16; ++r) {
          int srcl = (r & 3) + 8 * (r >> 2) + hi4;
          float cr = __shfl(corr, srcl, 64);
          o0[r] *= cr; o1[r] *= cr; o2[r] *= cr; o3[r] *= cr;
        }
      }
      float rs = 0.f;
#pragma unroll
      for (int r = 0; r < 16; ++r) {
        p0v[r] = __expf(p0v[r] - mrow);
        p1v[r] = __expf(p1v[r] - mrow);
        rs += p0v[r] + p1v[r];
      }
      rs += __shfl_xor(rs, 32, 64);
      lsum += rs;

      auto pv = [&](const f32x16& pk, int kvs) {
#pragma unroll
        for (int e = 0; e < 2; ++e) {
          u32 A = packbf(pk[e * 8 + 0], pk[e * 8 + 1]);
          u32 Bw = packbf(pk[e * 8 + 2], pk[e * 8 + 3]);
          u32 C = packbf(pk[e * 8 + 4], pk[e * 8 + 5]);
          u32 Dw = packbf(pk[e * 8 + 6], pk[e * 8 + 7]);
          u32 sA = __shfl_xor(A, 32, 64), sC = __shfl_xor(C, 32, 64);
          u32 sB = __shfl_xor(Bw, 32, 64), sD = __shfl_xor(Dw, 32, 64);
          union { u32 w[4]; bf16x8 v; } fr;
          fr.w[0] = hi ? sC : A;
          fr.w[1] = hi ? sD : Bw;
          fr.w[2] = hi ? C : sA;
          fr.w[3] = hi ? Dw : sB;
          int off = (kvs * 2 + e) * 32 + hi16;
          __builtin_amdgcn_s_setprio(1);
          o0 = mfma32(fr.v, *(const bf16x8*)((const char*)Vl + d0 * 128 + (off ^ vk0)), o0);
          o1 = mfma32(fr.v, *(const bf16x8*)((const char*)Vl + d1 * 128 + (off ^ vk1)), o1);
          o2 = mfma32(fr.v, *(const bf16x8*)((const char*)Vl + d2 * 128 + (off ^ vk2)), o2);
          o3 = mfma32(fr.v, *(const bf16x8*)((const char*)Vl + d3 * 128 + (off ^ vk3)), o3);
          __builtin_amdgcn_s_setprio(0);
        }
      };
      pv(p0v, 0);
      pv(p1v, 1);
    };

    loadV(0);
    stageK(0, 0);
    packV(0);
    __syncthreads();

    for (int t = 0; t < nt; ++t) {
      int cur = t & 1, nxt = cur ^ 1;
      bool more = (t + 1) < nt;
      if (more) {
        loadV((t + 1) * 64);
        stageK(nxt, (t + 1) * 64);
      }
      if (t <= lim) tile(t * 64, &Ks[cur][0], &Vs[cur][0]);
      if (more) packV(nxt);
      __syncthreads();
    }

#pragma unroll
    for (int r = 0; r < 16; ++r) {
      int ql = (r & 3) + 8 * (r >> 2) + hi4;
      float ls = __shfl(lsum, ql, 64);
      float inv = 1.0f / ls;
      size_t base = (tokb + chb + wave * 32 + ql) * (size_t)DMODEL + h * HD + qn;
      O[base] = f2bf(o0[r] * inv);
      O[base + 32] = f2bf(o1[r] * inv);
      O[base + 64] = f2bf(o2[r] * inv);
      O[base + 96] = f2bf(o3[r] * inv);
    }
  }
}

extern "C" void kernel_launch(void* const* d_in, const int* in_sizes, int n_in,
                              void* d_out, int out_size, void* d_ws, size_t ws_size,
                              hipStream_t stream) {
  const float* x  = (const float*)d_in[0];
  const float* Wq = (const float*)d_in[1];
  const float* Wk = (const float*)d_in[2];
  const float* Wv = (const float*)d_in[3];
  const float* Wo = (const float*)d_in[4];
  const float* qw = (const float*)d_in[5];
  const float* kw = (const float*)d_in[6];
  float* out = (float*)d_out;

  // Workspace (128 MiB):
  //   [0,   32M)  xb (bf16 x)  -- dead after GEMM1 -> reused as Wot
  //   [32M, 64M)  AO (attn out; region dead after GEMM1)
  //   [32M, 80M)  Wqkvt        -- dead after GEMM1
  //   [80M, 128M) QKVb
  char* ws = (char*)d_ws;
  u16* xb    = (u16*)(ws);
  u16* Wqkvt = (u16*)(ws + 33554432);
  u16* QKVb  = (u16*)(ws + 83886080);
  u16* Wot   = xb;
  u16* AO    = Wqkvt;

  // merged cvt + Wq/Wk/Wv transpose
  prep<<<2048 + 96 * (DMODEL / 64), 256, 0, stream>>>(x, xb, Wq, Wk, Wv, Wqkvt);

  // gemm1: 128x192 tile -> 1024 blocks = 2 exact generations at 2 blocks/CU
  gemm_db192<u16><<<(4096 / 128) * (QKVN / 192), 256, 0, stream>>>(xb, Wqkvt, QKVb, 4096, QKVN, DMODEL);

  // merged normrope (40960 blocks) + Wo transpose (4096 blocks)
  post1<<<40960 + 64 * (DMODEL / 64), 256, 0, stream>>>(QKVb, qw, kw, Wo, Wot);

  attn<<<256, 512, 0, stream>>>(QKVb, AO);
  // gemm2: 1024 blocks -> double-buffer template (2 blocks/CU, exactly 2 generations)
  gemm_db<float><<<(4096 / 128) * (DMODEL / 128), 256, 0, stream>>>(AO, Wot, out, 4096, DMODEL, DMODEL);
}